// Round 5
// baseline (150.257 us; speedup 1.0000x reference)
//
#include <hip/hip_runtime.h>

// CorrelationLayer: out[1,49,H,W], out[j*7+i,h,w] = sum_c x[c,h,w]*y[c,h+j-3,w+i-3]
// B=1, C=128, H=384, W=512, zero padding outside y.
//
// R5 = R4 + latency/ILP attack:
//  (a) divergent per-channel `if (eload)` removed: the halo-edge address is
//      wave-uniform (seg0 -> y[r,256..259], seg1 -> y[r,252..255]); load it
//      unconditionally (uniform addr = 1 cache line) and fold image-boundary
//      zeros into the existing lane-edge selects. Loop specialized on seg.
//  (b) explicit software pipeline: prefetch channel c+1's loads (y, x, edge)
//      into rotating registers before computing channel c.
// Geometry unchanged from R4: 768 blocks (row x half-row), 7 waves = disp row,
// lane = 4 px, halo via 6 unconditional ds_bpermute + cndmask.

constexpr int C = 128;
constexpr int H = 384;
constexpr int W = 512;
constexpr int HW = H * W;

__device__ __forceinline__ float bperm(int addr, float v) {
  return __int_as_float(__builtin_amdgcn_ds_bpermute(addr, __float_as_int(v)));
}

template <int SEG>
__device__ __forceinline__ void corr_loop(const float* __restrict__ xp,
                                          const float* __restrict__ yp,
                                          const float* __restrict__ ep,
                                          int lane, float acc[7][4]) {
  const int upA = ((lane - 1) & 63) << 2;
  const int dnA = ((lane + 1) & 63) << 2;
  const bool lo = (lane == 0);
  const bool hi = (lane == 63);

  float4 yv = *reinterpret_cast<const float4*>(yp);
  float4 xv = *reinterpret_cast<const float4*>(xp);
  float4 ev = *reinterpret_cast<const float4*>(ep);

#pragma unroll 2
  for (int c = 0; c < C; ++c) {
    float4 yn, xn, en;
    if (c + 1 < C) {                      // prefetch next channel
      yp += HW; xp += HW; ep += HW;
      yn = *reinterpret_cast<const float4*>(yp);
      xn = *reinterpret_cast<const float4*>(xp);
      en = *reinterpret_cast<const float4*>(ep);
    }

    // Unconditional cross-lane pulls (full exec mask; never inside branches).
    const float hl1 = bperm(upA, yv.y);   // y[w0-3] for lanes 1..63
    const float hl2 = bperm(upA, yv.z);
    const float hl3 = bperm(upA, yv.w);
    const float hr0 = bperm(dnA, yv.x);   // y[w0+4] for lanes 0..62
    const float hr1 = bperm(dnA, yv.y);
    const float hr2 = bperm(dnA, yv.z);

    // window wq[1..10] = y[r, w0-3 .. w0+6]
    float wq[12];
    if (SEG == 0) {
      // lane0 left halo = image boundary -> zeros; lane63 right halo = ev
      wq[1]  = lo ? 0.f : hl1;
      wq[2]  = lo ? 0.f : hl2;
      wq[3]  = lo ? 0.f : hl3;
      wq[8]  = hi ? ev.x : hr0;
      wq[9]  = hi ? ev.y : hr1;
      wq[10] = hi ? ev.z : hr2;
    } else {
      // lane0 left halo = ev; lane63 right halo = image boundary -> zeros
      wq[1]  = lo ? ev.y : hl1;
      wq[2]  = lo ? ev.z : hl2;
      wq[3]  = lo ? ev.w : hl3;
      wq[8]  = hi ? 0.f : hr0;
      wq[9]  = hi ? 0.f : hr1;
      wq[10] = hi ? 0.f : hr2;
    }
    wq[4] = yv.x; wq[5] = yv.y; wq[6] = yv.z; wq[7] = yv.w;

    const float xs[4] = {xv.x, xv.y, xv.z, xv.w};
    // out pixel w0+p, disp i: needs y[w0+p+i-3] = wq[p+i+1]
#pragma unroll
    for (int i = 0; i < 7; ++i)
#pragma unroll
      for (int p = 0; p < 4; ++p)
        acc[i][p] = fmaf(xs[p], wq[p + i + 1], acc[i][p]);

    yv = yn; xv = xn; ev = en;            // rotate pipeline registers
  }
}

__global__ __launch_bounds__(448, 6)
void corr_kernel(const float* __restrict__ x,
                 const float* __restrict__ y,
                 float* __restrict__ out) {
  const int bid   = blockIdx.x;
  const int idx   = bid >> 3;             // 0..95 within XCD
  const int h     = (bid & 7) * 48 + (idx >> 1);
  const int seg   = idx & 1;
  const int wbase = seg * 256;            // half-row segment
  const int j     = threadIdx.x >> 6;     // 0..6, displacement row
  const int lane  = threadIdx.x & 63;
  const int r     = h + j - 3;            // y row for this wave

  float acc[7][4];
#pragma unroll
  for (int i = 0; i < 7; ++i)
#pragma unroll
    for (int p = 0; p < 4; ++p) acc[i][p] = 0.f;

  const int w0 = wbase + lane * 4;        // first output pixel of this lane

  if (r >= 0 && r < H) {
    // wave-uniform edge address: seg0 lane63 needs y[256..259],
    // seg1 lane0 needs y[252..255]
    const int euni = (seg == 0) ? 256 : 252;
    const float* xp = x + (size_t)h * W + w0;
    const float* yp = y + (size_t)r * W + w0;
    const float* ep = y + (size_t)r * W + euni;
    if (seg == 0) corr_loop<0>(xp, yp, ep, lane, acc);
    else          corr_loop<1>(xp, yp, ep, lane, acc);
  }

#pragma unroll
  for (int i = 0; i < 7; ++i) {
    float* o = out + (size_t)(j * 7 + i) * HW + (size_t)h * W + w0;
    *reinterpret_cast<float4*>(o) =
        make_float4(acc[i][0], acc[i][1], acc[i][2], acc[i][3]);
  }
}

extern "C" void kernel_launch(void* const* d_in, const int* in_sizes, int n_in,
                              void* d_out, int out_size, void* d_ws, size_t ws_size,
                              hipStream_t stream) {
  const float* x = (const float*)d_in[0];
  const float* y = (const float*)d_in[1];
  float* out = (float*)d_out;
  corr_kernel<<<dim3(H * 2), dim3(448), 0, stream>>>(x, y, out);
}

// Round 6
// 99.741 us; speedup vs baseline: 1.5065x; 1.5065x over previous
//
#include <hip/hip_runtime.h>
#include <stdint.h>

// CorrelationLayer via MFMA Gram tiles.
// out[j*7+i, h, w] = sum_c x[c,h,w] * y[c,h+j-3,w+i-3], zero-padded.
//
// R6: per wave-unit (h, ws 16-wide): A = x[c, h, ws..ws+15] (M=16, K=128,
// bf16). For each j: B tiles = y[c, r, ws-3..ws+12] and y[c, r, ws+13..ws+18]
// (N=16 each; tile1 cols >= ws+19 are never read from C, garbage OK).
// G = A^T-style Gram via 8x mfma_f32_16x16x32_bf16; out[i][ws+m] = G[m][m+i]
// extracted through a per-wave LDS slab (16x34 fp32, pad 34 -> <=2-way bank).
// Fragment layouts: A/B lane l: {m|n}=l&15, k=(l>>4)*8+e; C/D: col=lane&15,
// row=(lane>>4)*4+reg (guide m89-verified).
// bf16 rounding error: sigma ~0.018 per output, max ~0.1 << 1.22 threshold.
// Grid: 384 h x 8 slabs(64px) = 3072 blocks x 4 waves (wave = 16px tile).
// XCD-contiguous swizzle: XCD k owns rows [48k, 48k+48).

typedef __attribute__((ext_vector_type(8))) short short8;
typedef __attribute__((ext_vector_type(4))) float floatx4;

constexpr int C = 128;
constexpr int H = 384;
constexpr int W = 512;
constexpr int HW = H * W;

// pack two floats to bf16 pair (round-to-nearest, ties away) in one u32
__device__ __forceinline__ uint32_t pkbf(float a, float b) {
  uint32_t ua = (__float_as_uint(a) + 0x8000u) >> 16;
  uint32_t ub = (__float_as_uint(b) + 0x8000u) & 0xffff0000u;
  return ua | ub;
}

union S8U { uint32_t u[4]; short8 s; };

template <int EDGE>  // 0 interior, 1 left (ws==0), 2 right (ws==W-16)
__device__ __forceinline__ void corr_unit(const float* __restrict__ x,
                                          const float* __restrict__ y,
                                          float* __restrict__ out,
                                          int h, int ws, int lane,
                                          float* __restrict__ gslab) {
  const int m = lane & 15;   // A row = x col offset = out w offset
  const int g = lane >> 4;   // k-group (and extraction i-group)

  // ---- A fragments: A[m][k] = x[k][h][ws+m], k = kt*32 + g*8 + e ----
  short8 af[4];
  {
    const float* xb = x + (size_t)(g * 8) * HW + (size_t)h * W + (ws + m);
#pragma unroll
    for (int kt = 0; kt < 4; ++kt) {
      float f[8];
#pragma unroll
      for (int e = 0; e < 8; ++e) f[e] = xb[(size_t)(kt * 32 + e) * HW];
      S8U s;
#pragma unroll
      for (int p = 0; p < 4; ++p) s.u[p] = pkbf(f[2 * p], f[2 * p + 1]);
      af[kt] = s.s;
    }
  }

  // B column addresses (per-lane, fixed across j/kt)
  int col0 = ws - 3 + m;    // tile0: slab cols 0..15  (abs ws-3 .. ws+12)
  int col1 = ws + 13 + m;   // tile1: slab cols 16..21 used (abs ws+13..ws+18)
  bool inv0 = false, inv1 = false;
  if (EDGE == 1) { inv0 = (col0 < 0);  if (inv0) col0 = 0; }
  if (EDGE == 2) { inv1 = (col1 >= W); if (inv1) col1 = W - 1; }

#pragma unroll 1
  for (int j = 0; j < 7; ++j) {
    const int r = h + j - 3;
    float vo0 = 0.f, vo1 = 0.f;
    if (r >= 0 && r < H) {
      const float* yb = y + (size_t)(g * 8) * HW + (size_t)r * W;
      floatx4 c0 = {0.f, 0.f, 0.f, 0.f};
      floatx4 c1 = {0.f, 0.f, 0.f, 0.f};
#pragma unroll
      for (int kt = 0; kt < 4; ++kt) {
        float f0[8], f1[8];
#pragma unroll
        for (int e = 0; e < 8; ++e) {
          f0[e] = yb[(size_t)(kt * 32 + e) * HW + col0];
          f1[e] = yb[(size_t)(kt * 32 + e) * HW + col1];
        }
        if (EDGE == 1) {
#pragma unroll
          for (int e = 0; e < 8; ++e) f0[e] = inv0 ? 0.f : f0[e];
        }
        if (EDGE == 2) {
#pragma unroll
          for (int e = 0; e < 8; ++e) f1[e] = inv1 ? 0.f : f1[e];
        }
        S8U b0, b1;
#pragma unroll
        for (int p = 0; p < 4; ++p) {
          b0.u[p] = pkbf(f0[2 * p], f0[2 * p + 1]);
          b1.u[p] = pkbf(f1[2 * p], f1[2 * p + 1]);
        }
        c0 = __builtin_amdgcn_mfma_f32_16x16x32_bf16(af[kt], b0.s, c0, 0, 0, 0);
        c1 = __builtin_amdgcn_mfma_f32_16x16x32_bf16(af[kt], b1.s, c1, 0, 0, 0);
      }
      // ---- extraction: write G slab, read diagonals (same wave, no barrier)
#pragma unroll
      for (int q = 0; q < 4; ++q) {
        gslab[(g * 4 + q) * 34 + m]      = c0[q];   // rows g*4+q, cols 0..15
        gslab[(g * 4 + q) * 34 + 16 + m] = c1[q];   // cols 16..31
      }
      // out[i][ws+m] = G[m][m+i]; lane (g,m) handles i = g and i = g+4
      vo0 = gslab[m * 34 + (m + g)];
      vo1 = gslab[m * 34 + (m + g + 4)];
    }
    float* ob = out + (size_t)(j * 7 + g) * HW + (size_t)h * W + (ws + m);
    *ob = vo0;                              // plane j*7+g      (i = g)
    if (g < 3) ob[(size_t)4 * HW] = vo1;    // plane j*7+g+4    (i = g+4)
  }
}

__global__ __launch_bounds__(256, 4)
void corr_mfma(const float* __restrict__ x, const float* __restrict__ y,
               float* __restrict__ out) {
  __shared__ float gs[4][16 * 34];
  const int bid  = blockIdx.x;
  const int idx  = bid >> 3;              // 0..383 within XCD
  const int h    = (bid & 7) * 48 + (idx >> 3);
  const int slab = idx & 7;
  const int wv   = threadIdx.x >> 6;
  const int lane = threadIdx.x & 63;
  const int ws   = slab * 64 + wv * 16;

  if (ws == 0)           corr_unit<1>(x, y, out, h, ws, lane, gs[wv]);
  else if (ws == W - 16) corr_unit<2>(x, y, out, h, ws, lane, gs[wv]);
  else                   corr_unit<0>(x, y, out, h, ws, lane, gs[wv]);
}

extern "C" void kernel_launch(void* const* d_in, const int* in_sizes, int n_in,
                              void* d_out, int out_size, void* d_ws, size_t ws_size,
                              hipStream_t stream) {
  const float* x = (const float*)d_in[0];
  const float* y = (const float*)d_in[1];
  float* out = (float*)d_out;
  corr_mfma<<<dim3(384 * 8), dim3(256), 0, stream>>>(x, y, out);
}

// Round 7
// 82.384 us; speedup vs baseline: 1.8238x; 1.2107x over previous
//
#include <hip/hip_runtime.h>
#include <stdint.h>

// CorrelationLayer via MFMA Gram tiles, LDS-staged B operand.
// out[j*7+i, h, w] = sum_c x[c,h,w] * y[c,h+j-3,w+i-3], zero-padded.
//
// R7: block = (h, 64-px slab), 4 waves, wave = 16-px tile. Channel chunks of
// K=32: stage y[chunk][h-3..h+3][ws-3..ws+66] to LDS bf16 [row7][col70][k40]
// (k-contiguous -> B frag = 1 ds_read_b128; pad 40 -> 80B/col, 16B-aligned,
// bank-uniform). Compute: per chunk, A frag direct-global (8 coalesced
// stride-HW loads), then 7j x 2tiles x (ds_read_b128 + mfma_16x16x32_bf16),
// acc[7][2] persists across chunks. OOB rows/cols zeroed in staging ->
// branch-free compute. Diagonal extraction via per-wave LDS slab (reuses y_s
// after barrier) exactly as R6 (verified: A/B lane {m|n}=l&15,k=(l>>4)*8+e;
// C/D col=lane&15,row=(lane>>4)*4+reg; i = n-m; vo0 i=g, vo1 i=g+4 (g<3)).
// Grid 384h x 8 slabs = 3072 blocks; XCD swizzle: XCD k owns rows [48k,48k+48).

typedef __attribute__((ext_vector_type(8))) short short8;
typedef __attribute__((ext_vector_type(4))) float floatx4;

constexpr int C = 128;
constexpr int H = 384;
constexpr int W = 512;
constexpr int HW = H * W;

constexpr int NROW = 7;
constexpr int NCOL = 70;   // 64 px + 3 halo each side
constexpr int KP   = 40;   // k padded 32->40 bf16 (80B col stride)

__device__ __forceinline__ uint32_t pkbf(float a, float b) {
  uint32_t ua = (__float_as_uint(a) + 0x8000u) >> 16;
  uint32_t ub = (__float_as_uint(b) + 0x8000u) & 0xffff0000u;
  return ua | ub;
}

union S8U { uint32_t u[4]; short8 s; };

__global__ __launch_bounds__(256, 4)
void corr_mfma(const float* __restrict__ x, const float* __restrict__ y,
               float* __restrict__ out) {
  __shared__ uint16_t ys[NROW * NCOL * KP];   // 39200 B

  const int bid    = blockIdx.x;
  const int idx    = bid >> 3;                // 0..383 within XCD
  const int h      = (bid & 7) * 48 + (idx >> 3);
  const int slab   = idx & 7;
  const int ws_blk = slab * 64;
  const int tid    = threadIdx.x;
  const int wv     = tid >> 6;
  const int lane   = tid & 63;
  const int m      = lane & 15;
  const int g      = lane >> 4;

  floatx4 acc[7][2];
#pragma unroll
  for (int j = 0; j < 7; ++j) {
    acc[j][0] = (floatx4){0.f, 0.f, 0.f, 0.f};
    acc[j][1] = (floatx4){0.f, 0.f, 0.f, 0.f};
  }

  // per-lane LDS fragment base (bf16-element index), tile0 / tile1
  const int colA = wv * 16 + m;               // 0..63
  int colB = wv * 16 + 16 + m;                // clamp: only unused lanes OOB
  if (colB > NCOL - 1) colB = NCOL - 1;
  const int fb0 = colA * KP + g * 8;
  const int fb1 = colB * KP + g * 8;

  for (int kc = 0; kc < 4; ++kc) {            // channel chunks of 32
    __syncthreads();                          // protect previous chunk reads
    // ---- stage y chunk: 7 rows x 70 cols x 4 k-blocks(8) = 1960 units ----
#pragma unroll
    for (int it = 0; it < 8; ++it) {
      const int u = it * 256 + tid;
      if (u < NROW * 4 * NCOL) {
        const int row = u / 280;              // 280 = 4*70
        const int rem = u - row * 280;
        const int kb  = rem / 70;
        const int col = rem - kb * 70;
        const int r_abs = h - 3 + row;
        const int c_abs = ws_blk - 3 + col;
        const bool valid = (r_abs >= 0) & (r_abs < H) &
                           (c_abs >= 0) & (c_abs < W);
        int r_cl = r_abs < 0 ? 0 : (r_abs >= H ? H - 1 : r_abs);
        int c_cl = c_abs < 0 ? 0 : (c_abs >= W ? W - 1 : c_abs);
        const float* src = y + (size_t)(kc * 32 + kb * 8) * HW +
                           (size_t)r_cl * W + c_cl;
        float f[8];
#pragma unroll
        for (int e = 0; e < 8; ++e) {
          float t = src[(size_t)e * HW];
          f[e] = valid ? t : 0.f;
        }
        uint32_t pk0 = pkbf(f[0], f[1]);
        uint32_t pk1 = pkbf(f[2], f[3]);
        uint32_t pk2 = pkbf(f[4], f[5]);
        uint32_t pk3 = pkbf(f[6], f[7]);
        uint16_t* dst = &ys[(row * NCOL + col) * KP + kb * 8];
        *reinterpret_cast<uint4*>(dst) = make_uint4(pk0, pk1, pk2, pk3);
      }
    }
    __syncthreads();

    // ---- A fragment: x[kc*32 + g*8 + e][h][ws_blk + wv*16 + m] ----
    short8 af;
    {
      const float* xb = x + (size_t)(kc * 32 + g * 8) * HW +
                        (size_t)h * W + (ws_blk + wv * 16 + m);
      float f[8];
#pragma unroll
      for (int e = 0; e < 8; ++e) f[e] = xb[(size_t)e * HW];
      S8U s;
      s.u[0] = pkbf(f[0], f[1]);
      s.u[1] = pkbf(f[2], f[3]);
      s.u[2] = pkbf(f[4], f[5]);
      s.u[3] = pkbf(f[6], f[7]);
      af = s.s;
    }

    // ---- compute: 7 j x 2 tiles, B frag = 1 ds_read_b128 (imm offsets) ----
#pragma unroll
    for (int j = 0; j < 7; ++j) {
      const short8 b0 =
          *reinterpret_cast<const short8*>(&ys[j * (NCOL * KP) + fb0]);
      const short8 b1 =
          *reinterpret_cast<const short8*>(&ys[j * (NCOL * KP) + fb1]);
      acc[j][0] = __builtin_amdgcn_mfma_f32_16x16x32_bf16(af, b0, acc[j][0], 0, 0, 0);
      acc[j][1] = __builtin_amdgcn_mfma_f32_16x16x32_bf16(af, b1, acc[j][1], 0, 0, 0);
    }
  }

  // ---- extraction: per-wave slab (reuse ys after all reads done) ----
  __syncthreads();
  float* slabp = reinterpret_cast<float*>(ys) + wv * 544;  // 16x34 f32
#pragma unroll
  for (int j = 0; j < 7; ++j) {
#pragma unroll
    for (int q = 0; q < 4; ++q) {
      slabp[(g * 4 + q) * 34 + m]      = acc[j][0][q];   // cols 0..15
      slabp[(g * 4 + q) * 34 + 16 + m] = acc[j][1][q];   // cols 16..31
    }
    const float vo0 = slabp[m * 34 + m + g];       // i = g
    const float vo1 = slabp[m * 34 + m + g + 4];   // i = g+4 (g<3)
    float* ob = out + (size_t)(j * 7 + g) * HW + (size_t)h * W +
                (ws_blk + wv * 16 + m);
    *ob = vo0;
    if (g < 3) ob[(size_t)4 * HW] = vo1;
  }
}

extern "C" void kernel_launch(void* const* d_in, const int* in_sizes, int n_in,
                              void* d_out, int out_size, void* d_ws, size_t ws_size,
                              hipStream_t stream) {
  const float* x = (const float*)d_in[0];
  const float* y = (const float*)d_in[1];
  float* out = (float*)d_out;
  corr_mfma<<<dim3(384 * 8), dim3(256), 0, stream>>>(x, y, out);
}